// Round 2
// baseline (1459.214 us; speedup 1.0000x reference)
//
#include <hip/hip_runtime.h>
#include <hip/hip_bf16.h>

// ---------------- problem constants ----------------
#define BB    128
#define TT    65536
#define LF    32
#define HOP   16
#define DELTA 3
#define HID   32
#define GRUH  64
#define SWIN  96          // DELTA*HOP*2
#define SHOP  48          // DELTA*HOP
#define NF    4095        // (TT-LF)/HOP + 1
#define NS    1364        // (TT-SWIN)/SHOP + 1

// ---------------- ws layout (float indices) ----------------
#define GI_BASE   0ull                                        // gi: [B][NS][192] fp32
#define GB_BASE   (GI_BASE + (unsigned long long)BB*NS*192)   // gb: [B][NS][64] fp32 (g|b)

__device__ __forceinline__ float sigmoidf_(float x) {
    return 1.f / (1.f + __expf(-x));
}
__device__ __forceinline__ float tanhf_(float x) {
    float e = __expf(-2.f * fabsf(x));
    float r = (1.f - e) / (1.f + e);
    return copysignf(r, x);
}

// ---------------- K1: gi[b][n][j] = b_ih[j] + slow_frame(b,n) . w_ih[j,:] ----------------
// block = 192 threads (one per output row j), 8 slow frames per block, x staged in LDS.
__global__ __launch_bounds__(192) void k1_gi(const float* __restrict__ x,
                                             const float* __restrict__ wih,
                                             const float* __restrict__ bih,
                                             float* __restrict__ gi) {
    int b  = blockIdx.y;
    int n0 = blockIdx.x * 8;
    int tid = threadIdx.x;                 // 0..191 = output row j
    __shared__ __align__(16) float xs[8 * SHOP + SHOP];   // 432 floats
    const float* xb = x + (size_t)b * TT + (size_t)n0 * SHOP;
    int lim = TT - n0 * SHOP;
    for (int i = tid; i < 432; i += 192)
        xs[i] = (i < lim) ? xb[i] : 0.f;

    float w[96];
    const float4* wrow = (const float4*)(wih + tid * 96);
#pragma unroll
    for (int k4 = 0; k4 < 24; ++k4) {
        float4 v = wrow[k4];
        w[4*k4+0] = v.x; w[4*k4+1] = v.y; w[4*k4+2] = v.z; w[4*k4+3] = v.w;
    }
    float bias = bih[tid];
    __syncthreads();
#pragma unroll
    for (int f = 0; f < 8; ++f) {
        int n = n0 + f;
        if (n >= NS) break;
        const float* xf = xs + f * SHOP;
        float acc = bias;
#pragma unroll
        for (int k = 0; k < 96; ++k) acc = fmaf(xf[k], w[k], acc);
        gi[((size_t)b * NS + n) * 192 + tid] = acc;
    }
}

// ---------------- K2: GRU scan + fused out-projection ----------------
// 1 block per batch element. threads 0..191: recurrence rows (w_hh row in regs).
// threads 192..255: out-projection of h_{t-1} (runs concurrently on 4th wave).
__global__ __launch_bounds__(256, 1) void k2_scan(const float* __restrict__ whh,
                                                  const float* __restrict__ bhh,
                                                  const float* __restrict__ outw,
                                                  const float* __restrict__ outb,
                                                  const float* __restrict__ gi,
                                                  float* __restrict__ gb) {
    int b = blockIdx.x;
    int tid = threadIdx.x;
    __shared__ __align__(16) float h[GRUH];
    __shared__ float pr[GRUH], pz[GRUH], pnh[GRUH], pni[GRUH];

    float w[64];
    float bias;
    if (tid < 192) {
        const float4* wr = (const float4*)(whh + tid * 64);
#pragma unroll
        for (int k4 = 0; k4 < 16; ++k4) {
            float4 v = wr[k4];
            w[4*k4] = v.x; w[4*k4+1] = v.y; w[4*k4+2] = v.z; w[4*k4+3] = v.w;
        }
        bias = bhh[tid];
    } else {
        int o = tid - 192;
        const float4* wr = (const float4*)(outw + o * 64);
#pragma unroll
        for (int k4 = 0; k4 < 16; ++k4) {
            float4 v = wr[k4];
            w[4*k4] = v.x; w[4*k4+1] = v.y; w[4*k4+2] = v.z; w[4*k4+3] = v.w;
        }
        bias = outb[o];
    }
    if (tid < GRUH) h[tid] = 0.f;

    const float* gptr = gi + ((size_t)b * NS) * 192 + tid;   // valid for tid<192
    float g0 = 0.f, g1 = 0.f, g2 = 0.f, g3 = 0.f;
    if (tid < 192) {
        g0 = gptr[0];
        g1 = gptr[192];
        g2 = gptr[2 * 192];
        g3 = gptr[3 * 192];
    }
    float* gbp = gb + ((size_t)b * NS) * 64 + (tid - 192);   // valid for tid>=192
    __syncthreads();

    for (int t = 0; t < NS; ++t) {
        if (tid < 192) {
            float acc = bias;
            const float4* h4 = (const float4*)h;
#pragma unroll
            for (int k4 = 0; k4 < 16; ++k4) {
                float4 hv = h4[k4];
                acc = fmaf(w[4*k4+0], hv.x, acc);
                acc = fmaf(w[4*k4+1], hv.y, acc);
                acc = fmaf(w[4*k4+2], hv.z, acc);
                acc = fmaf(w[4*k4+3], hv.w, acc);
            }
            float gcur = g0; g0 = g1; g1 = g2; g2 = g3;
            g3 = (t + 4 < NS) ? gptr[(size_t)(t + 4) * 192] : 0.f;
            if (tid < 64)       pr[tid] = gcur + acc;
            else if (tid < 128) pz[tid - 64] = gcur + acc;
            else              { pnh[tid - 128] = acc; pni[tid - 128] = gcur; }
        } else if (t > 0) {
            // out-projection of h_{t-1} (h[] still holds h_{t-1} in this phase)
            float acc = bias;
            const float4* h4 = (const float4*)h;
#pragma unroll
            for (int k4 = 0; k4 < 16; ++k4) {
                float4 hv = h4[k4];
                acc = fmaf(w[4*k4+0], hv.x, acc);
                acc = fmaf(w[4*k4+1], hv.y, acc);
                acc = fmaf(w[4*k4+2], hv.z, acc);
                acc = fmaf(w[4*k4+3], hv.w, acc);
            }
            gbp[(size_t)(t - 1) * 64] = acc;
        }
        __syncthreads();
        if (tid < 64) {
            float r  = sigmoidf_(pr[tid]);
            float z  = sigmoidf_(pz[tid]);
            float nn = tanhf_(fmaf(r, pnh[tid], pni[tid]));
            h[tid] = fmaf(z, h[tid] - nn, nn);   // (1-z)*n + z*h
        }
        __syncthreads();
    }
    // final out-projection for t = NS-1
    if (tid >= 192) {
        float acc = bias;
        const float4* h4 = (const float4*)h;
#pragma unroll
        for (int k4 = 0; k4 < 16; ++k4) {
            float4 hv = h4[k4];
            acc = fmaf(w[4*k4+0], hv.x, acc);
            acc = fmaf(w[4*k4+1], hv.y, acc);
            acc = fmaf(w[4*k4+2], hv.z, acc);
            acc = fmaf(w[4*k4+3], hv.w, acc);
        }
        gbp[(size_t)(NS - 1) * 64] = acc;
    }
}

// ---------------- K3: fast path fc1 -> FiLM -> relu -> fc2 -> overlap-add ----------------
// block handles one batch b and 64 output blocks-of-16; needs frames [m0-1, m0+64).
__global__ __launch_bounds__(256) void k3_fast(const float* __restrict__ x,
                                               const float* __restrict__ fc1w,
                                               const float* __restrict__ fc1b,
                                               const float* __restrict__ fc2w,
                                               const float* __restrict__ fc2b,
                                               const float* __restrict__ gb,
                                               float* __restrict__ out) {
    int b  = blockIdx.y;
    int m0 = blockIdx.x * 64;
    int tid = threadIdx.x;
    __shared__ __align__(16) float xs[65 * HOP + HOP];  // 1056
    __shared__ __align__(16) float h1s[65 * 32];
    __shared__ __align__(16) float ys[65 * 32];

    int  fbase  = m0 - 1;
    long xstart = (long)fbase * HOP;
    const float* xb = x + (size_t)b * TT;
    for (int i = tid; i < 1056; i += 256) {
        long p = xstart + i;
        xs[i] = (p >= 0 && p < TT) ? xb[p] : 0.f;
    }

    int j  = tid & 31;
    int fi = tid >> 5;
    float w1[32], w2[32];
    {
        const float4* r1 = (const float4*)(fc1w + j * 32);
        const float4* r2 = (const float4*)(fc2w + j * 32);
#pragma unroll
        for (int k4 = 0; k4 < 8; ++k4) {
            float4 v = r1[k4];
            w1[4*k4] = v.x; w1[4*k4+1] = v.y; w1[4*k4+2] = v.z; w1[4*k4+3] = v.w;
            float4 u = r2[k4];
            w2[4*k4] = u.x; w2[4*k4+1] = u.y; w2[4*k4+2] = u.z; w2[4*k4+3] = u.w;
        }
    }
    float b1 = fc1b[j];
    float b2 = fc2b[j];
    __syncthreads();

    // phase A: h1 = relu(g*fc1 + b)
    for (int ff = fi; ff < 65; ff += 8) {
        int f = fbase + ff;
        float v = 0.f;
        if (f >= 0 && f < NF) {
            float acc = b1;
            const float* xf = xs + ff * HOP;
#pragma unroll
            for (int k = 0; k < 32; ++k) acc = fmaf(xf[k], w1[k], acc);
            int sidx = f / DELTA - 1; if (sidx < 0) sidx = 0;
            const float* gp = gb + ((size_t)b * NS + sidx) * 64;
            v = fmaxf(fmaf(gp[j], acc, gp[32 + j]), 0.f);
        }
        h1s[ff * 32 + j] = v;
    }
    __syncthreads();

    // phase B: y = h1 @ fc2^T + fc2_b
    for (int ff = fi; ff < 65; ff += 8) {
        int f = fbase + ff;
        float v = 0.f;
        if (f >= 0 && f < NF) {
            float acc = b2;
            const float* hf = h1s + ff * 32;
#pragma unroll
            for (int k = 0; k < 32; ++k) acc = fmaf(hf[k], w2[k], acc);
            v = acc;
        }
        ys[ff * 32 + j] = v;
    }
    __syncthreads();

    // phase C: overlap-add -> out (fp32)
    float* ob = out + (size_t)b * TT + (size_t)m0 * HOP;
    for (int i = tid; i < 64 * 16; i += 256) {
        int ml = i >> 4, ii = i & 15;
        float v = ys[(ml + 1) * 32 + ii] + ys[ml * 32 + 16 + ii];
        ob[i] = v;
    }
}

// ---------------- launcher ----------------
extern "C" void kernel_launch(void* const* d_in, const int* in_sizes, int n_in,
                              void* d_out, int out_size, void* d_ws, size_t ws_size,
                              hipStream_t stream) {
    const float* x     = (const float*)d_in[0];
    const float* fc1w  = (const float*)d_in[1];
    const float* fc1b  = (const float*)d_in[2];
    const float* fc2w  = (const float*)d_in[3];
    const float* fc2b  = (const float*)d_in[4];
    const float* wih   = (const float*)d_in[5];
    const float* whh   = (const float*)d_in[6];
    const float* bih   = (const float*)d_in[7];
    const float* bhh   = (const float*)d_in[8];
    const float* outw  = (const float*)d_in[9];
    const float* outb  = (const float*)d_in[10];

    float* ws  = (float*)d_ws;
    float* gi  = ws + GI_BASE;
    float* gb  = ws + GB_BASE;
    float* out = (float*)d_out;

    k1_gi<<<dim3((NS + 7) / 8, BB), 192, 0, stream>>>(x, wih, bih, gi);

    k2_scan<<<BB, 256, 0, stream>>>(whh, bhh, outw, outb, gi, gb);

    k3_fast<<<dim3((NF + 1) / 64, BB), 256, 0, stream>>>(x, fc1w, fc1b, fc2w, fc2b, gb, out);
}

// Round 3
// 1043.720 us; speedup vs baseline: 1.3981x; 1.3981x over previous
//
#include <hip/hip_runtime.h>
#include <hip/hip_bf16.h>

// ---------------- problem constants ----------------
#define BB    128
#define TT    65536
#define LF    32
#define HOP   16
#define DELTA 3
#define HID   32
#define GRUH  64
#define SWIN  96          // DELTA*HOP*2
#define SHOP  48          // DELTA*HOP
#define NF    4095        // (TT-LF)/HOP + 1
#define NS    1364        // (TT-SWIN)/SHOP + 1

// ---------------- ws layout (float indices), total 178.8 MB (proven safe) ----
// gi : [B][NS][192] fp32 at 0            (134.1 MB)
// hs : [B][NS][64]  fp32 after gi        (44.7 MB)
// gb : [B][NS][64]  fp32 ALIASES gi (k2b writes after k2 finished reading gi)
#define GI_BASE   0ull
#define HS_BASE   (GI_BASE + (unsigned long long)BB*NS*192)
#define GB_BASE   0ull

typedef float v2f __attribute__((ext_vector_type(2)));

__device__ __forceinline__ float sigmoidf_(float x) {
    return 1.f / (1.f + __expf(-x));
}
__device__ __forceinline__ float tanhf_(float x) {
    float e = __expf(-2.f * fabsf(x));
    float r = (1.f - e) / (1.f + e);
    return copysignf(r, x);
}
__device__ __forceinline__ v2f pkfma(v2f a, v2f b, v2f c) {
    return __builtin_elementwise_fma(a, b, c);
}

// ---------------- K1: gi[b][n][j] = b_ih[j] + slow_frame(b,n) . w_ih[j,:] ----
// block = 192 threads (one per output row j), 8 slow frames per block.
__global__ __launch_bounds__(192) void k1_gi(const float* __restrict__ x,
                                             const float* __restrict__ wih,
                                             const float* __restrict__ bih,
                                             float* __restrict__ gi) {
    int b  = blockIdx.y;
    int n0 = blockIdx.x * 8;
    int tid = threadIdx.x;                 // 0..191 = output row j
    __shared__ __align__(16) float xs[8 * SHOP + SHOP];   // 432 floats
    const float* xb = x + (size_t)b * TT + (size_t)n0 * SHOP;
    int lim = TT - n0 * SHOP;
    for (int i = tid; i < 432; i += 192)
        xs[i] = (i < lim) ? xb[i] : 0.f;

    v2f w[48];
    const v2f* wrow = (const v2f*)(wih + tid * 96);
#pragma unroll
    for (int k = 0; k < 48; ++k) w[k] = wrow[k];
    float bias = bih[tid];
    __syncthreads();
#pragma unroll
    for (int f = 0; f < 8; ++f) {
        int n = n0 + f;
        if (n >= NS) break;
        const float4* xf4 = (const float4*)(xs + f * SHOP);  // 192B-aligned
        v2f a0 = {0.f, 0.f}, a1 = {0.f, 0.f};
#pragma unroll
        for (int k4 = 0; k4 < 24; ++k4) {
            float4 xv = xf4[k4];
            v2f p0; p0.x = xv.x; p0.y = xv.y;
            v2f p1; p1.x = xv.z; p1.y = xv.w;
            a0 = pkfma(w[2*k4],   p0, a0);
            a1 = pkfma(w[2*k4+1], p1, a1);
        }
        gi[((size_t)b * NS + n) * 192 + tid] = a0.x + a0.y + a1.x + a1.y + bias;
    }
}

// ---------------- K2: single-wave GRU scan ----------------
// 1 wave per batch element. Lane j owns W_hh rows {j, 64+j, 128+j} in regs
// (packed float2 -> v_pk_fma_f32). h broadcast via LDS; NO barriers (single
// wave: DS ops are in-order, compiler inserts lgkmcnt only).
__global__ __launch_bounds__(64, 1) void k2_scan(const float* __restrict__ whh,
                                                 const float* __restrict__ bhh,
                                                 const float* __restrict__ gi,
                                                 float* __restrict__ hs) {
    int b = blockIdx.x;
    int j = threadIdx.x;
    __shared__ __align__(16) float hsh[GRUH];

    v2f wr[32], wz[32], wn[32];
    const v2f* rr = (const v2f*)(whh + (size_t)j * 64);
    const v2f* rz = (const v2f*)(whh + (size_t)(64 + j) * 64);
    const v2f* rn = (const v2f*)(whh + (size_t)(128 + j) * 64);
#pragma unroll
    for (int k = 0; k < 32; ++k) { wr[k] = rr[k]; wz[k] = rz[k]; wn[k] = rn[k]; }
    float br = bhh[j], bz = bhh[64 + j], bn = bhh[128 + j];

    hsh[j] = 0.f;
    float hj = 0.f;
    const float* gp = gi + (size_t)b * NS * 192;
    float* hp = hs + (size_t)b * NS * 64 + j;

    // prefetch gi for t=0
    float gr0 = gp[j], gz0 = gp[64 + j], gn0 = gp[128 + j];

    for (int t = 0; t < NS; ++t) {
        // prefetch gi for t+1 (consumed ~1.5 iterations later)
        float gr1 = 0.f, gz1 = 0.f, gn1 = 0.f;
        if (t + 1 < NS) {
            const float* gq = gp + (size_t)(t + 1) * 192;
            gr1 = gq[j]; gz1 = gq[64 + j]; gn1 = gq[128 + j];
        }
        // gh = W_hh . h  (h read broadcast from LDS, written last iteration)
        v2f ar0 = {0.f,0.f}, ar1 = {0.f,0.f};
        v2f az0 = {0.f,0.f}, az1 = {0.f,0.f};
        v2f an0 = {0.f,0.f}, an1 = {0.f,0.f};
        const float4* h4 = (const float4*)hsh;
#pragma unroll
        for (int k4 = 0; k4 < 16; ++k4) {
            float4 hv = h4[k4];
            v2f p0; p0.x = hv.x; p0.y = hv.y;
            v2f p1; p1.x = hv.z; p1.y = hv.w;
            ar0 = pkfma(wr[2*k4],   p0, ar0);
            ar1 = pkfma(wr[2*k4+1], p1, ar1);
            az0 = pkfma(wz[2*k4],   p0, az0);
            az1 = pkfma(wz[2*k4+1], p1, az1);
            an0 = pkfma(wn[2*k4],   p0, an0);
            an1 = pkfma(wn[2*k4+1], p1, an1);
        }
        float sr = ar0.x + ar0.y + ar1.x + ar1.y + br;
        float sz = az0.x + az0.y + az1.x + az1.y + bz;
        float sn = an0.x + an0.y + an1.x + an1.y + bn;
        float r  = sigmoidf_(gr0 + sr);
        float z  = sigmoidf_(gz0 + sz);
        float nn = tanhf_(fmaf(r, sn, gn0));
        hj = fmaf(z, hj - nn, nn);           // (1-z)*n + z*h
        hsh[j] = hj;                         // next iter's reads ordered after
        hp[(size_t)t * 64] = hj;             // coalesced, fire-and-forget
        gr0 = gr1; gz0 = gz1; gn0 = gn1;
    }
}

// ---------------- K2b: out-projection GEMM  gb[b][t][o] = hs[b][t].outw[o]+outb[o]
__global__ __launch_bounds__(256) void k2b_proj(const float* __restrict__ outw,
                                                const float* __restrict__ outb,
                                                const float* __restrict__ hs,
                                                float* __restrict__ gb) {
    int b  = blockIdx.y;
    int t0 = blockIdx.x * 64;
    int tid = threadIdx.x;
    int o  = tid & 63, ts = tid >> 6;        // o = out row, ts in 0..3
    __shared__ __align__(16) float hsl[64 * 64];
    const float* hb = hs + ((size_t)b * NS + t0) * 64;
    int lim = (NS - t0) * 64;
    for (int i = tid; i < 4096; i += 256)
        hsl[i] = (i < lim) ? hb[i] : 0.f;

    v2f w[32];
    const v2f* wrow = (const v2f*)(outw + (size_t)o * 64);
#pragma unroll
    for (int k = 0; k < 32; ++k) w[k] = wrow[k];
    float bias = outb[o];
    __syncthreads();

    float* gbp = gb + ((size_t)b * NS + t0) * 64 + o;
    for (int tt = ts; tt < 64; tt += 4) {
        if (t0 + tt >= NS) break;
        const float4* h4 = (const float4*)(hsl + tt * 64);
        v2f a0 = {0.f,0.f}, a1 = {0.f,0.f};
#pragma unroll
        for (int k4 = 0; k4 < 16; ++k4) {
            float4 hv = h4[k4];
            v2f p0; p0.x = hv.x; p0.y = hv.y;
            v2f p1; p1.x = hv.z; p1.y = hv.w;
            a0 = pkfma(w[2*k4],   p0, a0);
            a1 = pkfma(w[2*k4+1], p1, a1);
        }
        gbp[(size_t)tt * 64] = a0.x + a0.y + a1.x + a1.y + bias;
    }
}

// ---------------- K3: fast path fc1 -> FiLM -> relu -> fc2 -> overlap-add ----
__global__ __launch_bounds__(256) void k3_fast(const float* __restrict__ x,
                                               const float* __restrict__ fc1w,
                                               const float* __restrict__ fc1b,
                                               const float* __restrict__ fc2w,
                                               const float* __restrict__ fc2b,
                                               const float* __restrict__ gb,
                                               float* __restrict__ out) {
    int b  = blockIdx.y;
    int m0 = blockIdx.x * 64;
    int tid = threadIdx.x;
    __shared__ __align__(16) float xs[65 * HOP + HOP];  // 1056
    __shared__ __align__(16) float h1s[65 * 32];
    __shared__ __align__(16) float ys[65 * 32];

    int  fbase  = m0 - 1;
    long xstart = (long)fbase * HOP;
    const float* xb = x + (size_t)b * TT;
    for (int i = tid; i < 1056; i += 256) {
        long p = xstart + i;
        xs[i] = (p >= 0 && p < TT) ? xb[p] : 0.f;
    }

    int j  = tid & 31;
    int fi = tid >> 5;
    v2f w1[16], w2[16];
    {
        const v2f* r1 = (const v2f*)(fc1w + (size_t)j * 32);
        const v2f* r2 = (const v2f*)(fc2w + (size_t)j * 32);
#pragma unroll
        for (int k = 0; k < 16; ++k) { w1[k] = r1[k]; w2[k] = r2[k]; }
    }
    float b1 = fc1b[j];
    float b2 = fc2b[j];
    __syncthreads();

    // phase A: h1 = relu(g*fc1 + b)
    for (int ff = fi; ff < 65; ff += 8) {
        int f = fbase + ff;
        float v = 0.f;
        if (f >= 0 && f < NF) {
            const float4* xf4 = (const float4*)(xs + ff * HOP);  // 64B-aligned
            v2f a0 = {0.f,0.f}, a1 = {0.f,0.f};
#pragma unroll
            for (int k4 = 0; k4 < 8; ++k4) {
                float4 xv = xf4[k4];
                v2f p0; p0.x = xv.x; p0.y = xv.y;
                v2f p1; p1.x = xv.z; p1.y = xv.w;
                a0 = pkfma(w1[2*k4],   p0, a0);
                a1 = pkfma(w1[2*k4+1], p1, a1);
            }
            float acc = a0.x + a0.y + a1.x + a1.y + b1;
            int sidx = f / DELTA - 1; if (sidx < 0) sidx = 0;
            const float* gp = gb + ((size_t)b * NS + sidx) * 64;
            v = fmaxf(fmaf(gp[j], acc, gp[32 + j]), 0.f);
        }
        h1s[ff * 32 + j] = v;
    }
    __syncthreads();

    // phase B: y = h1 @ fc2^T + fc2_b
    for (int ff = fi; ff < 65; ff += 8) {
        int f = fbase + ff;
        float v = 0.f;
        if (f >= 0 && f < NF) {
            const float4* hf4 = (const float4*)(h1s + ff * 32);  // 128B-aligned
            v2f a0 = {0.f,0.f}, a1 = {0.f,0.f};
#pragma unroll
            for (int k4 = 0; k4 < 8; ++k4) {
                float4 hv = hf4[k4];
                v2f p0; p0.x = hv.x; p0.y = hv.y;
                v2f p1; p1.x = hv.z; p1.y = hv.w;
                a0 = pkfma(w2[2*k4],   p0, a0);
                a1 = pkfma(w2[2*k4+1], p1, a1);
            }
            v = a0.x + a0.y + a1.x + a1.y + b2;
        }
        ys[ff * 32 + j] = v;
    }
    __syncthreads();

    // phase C: overlap-add -> out (fp32)
    float* ob = out + (size_t)b * TT + (size_t)m0 * HOP;
    for (int i = tid; i < 64 * 16; i += 256) {
        int ml = i >> 4, ii = i & 15;
        ob[i] = ys[(ml + 1) * 32 + ii] + ys[ml * 32 + 16 + ii];
    }
}

// ---------------- launcher ----------------
extern "C" void kernel_launch(void* const* d_in, const int* in_sizes, int n_in,
                              void* d_out, int out_size, void* d_ws, size_t ws_size,
                              hipStream_t stream) {
    const float* x     = (const float*)d_in[0];
    const float* fc1w  = (const float*)d_in[1];
    const float* fc1b  = (const float*)d_in[2];
    const float* fc2w  = (const float*)d_in[3];
    const float* fc2b  = (const float*)d_in[4];
    const float* wih   = (const float*)d_in[5];
    const float* whh   = (const float*)d_in[6];
    const float* bih   = (const float*)d_in[7];
    const float* bhh   = (const float*)d_in[8];
    const float* outw  = (const float*)d_in[9];
    const float* outb  = (const float*)d_in[10];

    float* ws  = (float*)d_ws;
    float* gi  = ws + GI_BASE;
    float* hs  = ws + HS_BASE;
    float* gb  = ws + GB_BASE;   // aliases gi: written only after k2 consumed gi
    float* out = (float*)d_out;

    k1_gi<<<dim3((NS + 7) / 8, BB), 192, 0, stream>>>(x, wih, bih, gi);

    k2_scan<<<BB, 64, 0, stream>>>(whh, bhh, gi, hs);

    k2b_proj<<<dim3((NS + 63) / 64, BB), 256, 0, stream>>>(outw, outb, hs, gb);

    k3_fast<<<dim3((NF + 1) / 64, BB), 256, 0, stream>>>(x, fc1w, fc1b, fc2w, fc2b, gb, out);
}